// Round 7
// baseline (161.718 us; speedup 1.0000x reference)
//
#include <hip/hip_runtime.h>
#include <cstddef>

// B=2048, C_IN=C_OUT=64, T=32, E=32768, K_HOPS=2, KSIZE=3
#define NB   2048
#define NE   32768
#define NTC  2048      // T*C elems per node
#define SLOPE_F 0.01f
#define EPS_F   1e-5f

typedef short bf16x8 __attribute__((ext_vector_type(8)));
typedef float f32x4  __attribute__((ext_vector_type(4)));

// bf16 helpers (manual, RNE pack)
__device__ __forceinline__ unsigned short f2bf(float f) {
    unsigned u = __builtin_bit_cast(unsigned, f);
    u += 0x7FFF + ((u >> 16) & 1);
    return (unsigned short)(u >> 16);
}
__device__ __forceinline__ float bflo(unsigned v) {
    return __builtin_bit_cast(float, v << 16);
}
__device__ __forceinline__ float bfhi(unsigned v) {
    return __builtin_bit_cast(float, v & 0xFFFF0000u);
}
__device__ __forceinline__ unsigned pk2(float lo, float hi) {
    return (unsigned)f2bf(lo) | ((unsigned)f2bf(hi) << 16);
}
// unpack-accumulate 4 bf16 lanes of a uint2 into acc[0..3]
__device__ __forceinline__ void accv4(float* acc, const uint2& v, float wt) {
    acc[0] += wt * bflo(v.x); acc[1] += wt * bfhi(v.x);
    acc[2] += wt * bflo(v.y); acc[3] += wt * bfhi(v.y);
}
// unpack-accumulate 4 int16 lanes of a uint2 into acc[0..3] (wt has scale folded)
__device__ __forceinline__ void acci16_4(float* acc, const uint2& v, float wt) {
    acc[0] += wt * (float)(short)(v.x & 0xFFFFu); acc[1] += wt * (float)(short)(v.x >> 16);
    acc[2] += wt * (float)(short)(v.y & 0xFFFFu); acc[3] += wt * (float)(short)(v.y >> 16);
}
__device__ __forceinline__ unsigned pkq2(float a, float b, float inv) {
    int qa = __float2int_rn(a * inv);
    int qb = __float2int_rn(b * inv);
    return ((unsigned)qa & 0xFFFFu) | ((unsigned)qb << 16);
}
// split f into bf16 hi + bf16 lo (lo = exact fp32 residual, then RNE to bf16)
__device__ __forceinline__ void spl2(float a, float b, unsigned& hw, unsigned& lw) {
    unsigned short ha = f2bf(a), hb = f2bf(b);
    float ra = a - bflo((unsigned)ha);
    float rb = b - bflo((unsigned)hb);
    hw = (unsigned)ha | ((unsigned)hb << 16);
    lw = (unsigned)f2bf(ra) | ((unsigned)f2bf(rb) << 16);
}

// ---------------- edge-index width handling (per-wave ballot detect) -------
// int64 layout: high words ei[2e+1] all 0 (ids < 2048). int32 layout:
// P(64 sampled ids all zero) = 2048^-64 ~ 0. Wave-local ballot decides.
__device__ __forceinline__ int edge_src(const int* ei, int m, int e) {
    return m ? ei[e] : ei[2 * e];
}
__device__ __forceinline__ int edge_dst(const int* ei, int m, int e) {
    return m ? ei[NE + e] : ei[2 * (NE + e)];
}

// ---------------- dispatch 1: zero hist + pack weights ---------------------
//   blocks 0..47:   wAb[(kk*64+o)*64+i] = bf16 w[o][i][kk]    (conv A-layout)
//   blocks 48..95:  twB[m][g*64+k]      = bf16 tw[m][k][g]    (tag B-layout, W^T)
//   blocks 96..111: twBlo[g*64+k]       = bf16(W2 - bf16(W2)) (split-lo of W2)
//   first 2048 flat threads: hist = 0   (replaces hipMemsetAsync)
__global__ __launch_bounds__(256)
void k_pre(int* __restrict__ hist, const float* __restrict__ cw,
           unsigned short* __restrict__ wAb, const float* __restrict__ tw,
           unsigned short* __restrict__ twB, unsigned short* __restrict__ twBlo)
{
    int gid = blockIdx.x * 256 + threadIdx.x;
    if (gid < 2048) hist[gid] = 0;
    if (blockIdx.x < 48) {
        int idx = gid;                    // 0..12287
        int kk = idx >> 12, o = (idx >> 6) & 63, i = idx & 63;
        wAb[idx] = f2bf(cw[o * 192 + i * 3 + kk]);
    } else if (blockIdx.x < 96) {
        int idx = gid - 48 * 256;         // 0..12287
        int mm = idx >> 12, rem = idx & 4095;
        int g = rem >> 6, k = rem & 63;
        twB[idx] = f2bf(tw[mm * 4096 + k * 64 + g]);
    } else {                              // blocks 96..111: W2 split-lo
        int idx = gid - 96 * 256;         // 0..4095
        int g = idx >> 6, k = idx & 63;
        float v = tw[2 * 4096 + k * 64 + g];
        unsigned short hi = f2bf(v);
        twBlo[idx] = f2bf(v - bflo((unsigned)hi));
    }
}

// ---------------- dispatch 2: convln (blocks 0..2047) U hist (2048..2175) --
__global__ __launch_bounds__(256, 4)
void k_main(const float* __restrict__ x, const unsigned short* __restrict__ wAb,
            const float* __restrict__ cb, const float* __restrict__ lg,
            const float* __restrict__ lb, float* __restrict__ h_in,
            float* __restrict__ partials,
            const int* __restrict__ ei, int* __restrict__ hist)
{
    if (blockIdx.x >= NB) {               // ---- hist part (whole blocks) ----
        int e = (blockIdx.x - NB) * 256 + threadIdx.x;
        unsigned long long bal = __ballot(ei[2 * e + 1] != 0);
        int m = (bal != 0ull) ? 1 : 0;
        atomicAdd(&hist[edge_dst(ei, m, e)], 1);
        return;
    }
    __shared__ __align__(16) unsigned short xT[36 * 72];
    __shared__ float hT[32 * 65];
    __shared__ float red1[64], red2[64];
    __shared__ float wsum[8];
    __shared__ float bcast[2];

    const int b = blockIdx.x, j = threadIdx.x;
    const float* __restrict__ xg = x + (size_t)b * NTC;

    {   // stage x -> bf16 xT[t+2][i]; zero-pad rows 0,1,34,35
        unsigned* xTd = (unsigned*)xT;
        int t = j & 31, p = j >> 5;
#pragma unroll
        for (int r = 0; r < 4; ++r) {
            int i0 = (r * 8 + p) * 2;
            float v0 = xg[i0 * 32 + t];
            float v1 = xg[(i0 + 1) * 32 + t];
            xTd[(t + 2) * 36 + (i0 >> 1)] = pk2(v0, v1);
        }
        if (j < 72)       xTd[j] = 0u;
        else if (j < 144) xTd[1224 + (j - 72)] = 0u;   // rows 34,35
    }
    __syncthreads();

    const int lane = j & 63, w = j >> 6;
    const int n16 = lane & 15, quad = lane >> 4;

    bf16x8 afr[3][2];
#pragma unroll
    for (int kk = 0; kk < 3; ++kk)
#pragma unroll
        for (int s = 0; s < 2; ++s) {
            int off16 = (kk * 64 + w * 16 + n16) * 64 + s * 32 + quad * 8;
            afr[kk][s] = *(const bf16x8*)(wAb + off16);
        }

    f32x4 acc0 = {0.f, 0.f, 0.f, 0.f};
    f32x4 acc1 = {0.f, 0.f, 0.f, 0.f};
#pragma unroll
    for (int kk = 0; kk < 3; ++kk)
#pragma unroll
        for (int s = 0; s < 2; ++s) {
            bf16x8 b0 = *(const bf16x8*)(xT + (n16 + kk) * 72 + s * 32 + quad * 8);
            bf16x8 b1 = *(const bf16x8*)(xT + (16 + n16 + kk) * 72 + s * 32 + quad * 8);
            acc0 = __builtin_amdgcn_mfma_f32_16x16x32_bf16(afr[kk][s], b0, acc0, 0, 0, 0);
            acc1 = __builtin_amdgcn_mfma_f32_16x16x32_bf16(afr[kk][s], b1, acc1, 0, 0, 0);
        }

    float vals[2][4];
    float s1 = 0.f, s2 = 0.f;
#pragma unroll
    for (int r = 0; r < 4; ++r) {
        float cbv = cb[w * 16 + quad * 4 + r];
        float v0 = acc0[r] + cbv;
        float v1 = acc1[r] + cbv;
        v0 = (v0 >= 0.f) ? v0 : SLOPE_F * v0;
        v1 = (v1 >= 0.f) ? v1 : SLOPE_F * v1;
        vals[0][r] = v0; vals[1][r] = v1;
        s1 += v0 + v1; s2 += v0 * v0 + v1 * v1;
    }
#pragma unroll
    for (int off = 32; off > 0; off >>= 1) {
        s1 += __shfl_down(s1, off, 64);
        s2 += __shfl_down(s2, off, 64);
    }
    if (lane == 0) { wsum[w] = s1; wsum[4 + w] = s2; }
    __syncthreads();
    if (j == 0) {
        float S1 = wsum[0] + wsum[1] + wsum[2] + wsum[3];
        float S2 = wsum[4] + wsum[5] + wsum[6] + wsum[7];
        float mu  = S1 * (1.f / 2048.f);
        float var = S2 * (1.f / 2048.f) - mu * mu;
        bcast[0] = mu;
        bcast[1] = rsqrtf(var + EPS_F);
    }
    __syncthreads();
    const float mu = bcast[0], rs = bcast[1];
    float po1[4] = {0.f, 0.f, 0.f, 0.f}, po2[4] = {0.f, 0.f, 0.f, 0.f};
#pragma unroll
    for (int nt = 0; nt < 2; ++nt) {
        int t = nt * 16 + n16;
#pragma unroll
        for (int r = 0; r < 4; ++r) {
            int o = w * 16 + quad * 4 + r;
            float h = (vals[nt][r] - mu) * rs * lg[o * 32 + t] + lb[o * 32 + t];
            hT[t * 65 + o] = h;
            po1[r] += h; po2[r] += h * h;
        }
    }
#pragma unroll
    for (int off = 8; off > 0; off >>= 1) {
#pragma unroll
        for (int r = 0; r < 4; ++r) {
            po1[r] += __shfl_down(po1[r], off, 16);
            po2[r] += __shfl_down(po2[r], off, 16);
        }
    }
    if (n16 == 0) {
#pragma unroll
        for (int r = 0; r < 4; ++r) {
            int o = w * 16 + quad * 4 + r;
            red1[o] = po1[r];
            red2[o] = po2[r];
        }
    }
    __syncthreads();
    float* hb = h_in + (size_t)b * NTC;
#pragma unroll
    for (int r = 0; r < 8; ++r) {                  // coalesced h_in store
        int idx = j + r * 256;
        hb[idx] = hT[(idx >> 6) * 65 + (idx & 63)];
    }
    float* pb_ = partials + (size_t)b * 128;       // coalesced 512B store
    if (j < 64)       pb_[j] = red1[j];
    else if (j < 128) pb_[j] = red2[j - 64];
}

// ---------------- dispatch 3: scan (block 0) U bnred (blocks 1..64) --------
__global__ __launch_bounds__(256)
void k_mid(const int* __restrict__ hist, int* __restrict__ rowp,
           int* __restrict__ cur, const float* __restrict__ partials,
           const float* __restrict__ bg, const float* __restrict__ bb,
           float* __restrict__ stats)
{
    __shared__ int part[256];
    __shared__ float r1[4], r2[4];
    const int j = threadIdx.x;
    if (blockIdx.x == 0) {                // ---- CSR row-pointer scan ----
        int loc[8]; int s = 0;
#pragma unroll
        for (int r = 0; r < 8; ++r) { loc[r] = hist[j * 8 + r]; s += loc[r]; }
        part[j] = s;
        __syncthreads();
        for (int off = 1; off < 256; off <<= 1) {
            int v = (j >= off) ? part[j - off] : 0;
            __syncthreads();
            part[j] += v;
            __syncthreads();
        }
        int excl = part[j] - s;
#pragma unroll
        for (int r = 0; r < 8; ++r) {
            rowp[j * 8 + r] = excl;
            cur [j * 8 + r] = excl;
            excl += loc[r];
        }
        if (j == 255) rowp[2048] = excl;  // == NE
        return;
    }
    // ---- BN partial reduce, c = blockIdx.x - 1 ----
    const int c = blockIdx.x - 1;
    float s1 = 0.f, s2 = 0.f;
    for (int b = j; b < NB; b += 256) {
        const float* p = partials + (size_t)b * 128;
        s1 += p[c];
        s2 += p[64 + c];
    }
#pragma unroll
    for (int off = 32; off > 0; off >>= 1) {
        s1 += __shfl_down(s1, off, 64);
        s2 += __shfl_down(s2, off, 64);
    }
    if ((j & 63) == 0) { r1[j >> 6] = s1; r2[j >> 6] = s2; }
    __syncthreads();
    if (j == 0) {
        float S1 = r1[0] + r1[1] + r1[2] + r1[3];
        float S2 = r2[0] + r2[1] + r2[2] + r2[3];
        const float inv_n = 1.f / 65536.f;
        float mu  = S1 * inv_n;
        float var = S2 * inv_n - mu * mu;
        float rs  = rsqrtf(var + EPS_F);
        float sc  = bg[c] * rs;
        stats[128 + c] = sc;
        stats[192 + c] = bb[c] - mu * sc;
    }
}

// ---------------- dispatch 4: zlite (blocks 0..2047) U scat (2048..2175) ---
__global__ __launch_bounds__(256)
void k_zs(const float* __restrict__ h_in, const float* __restrict__ stats,
          unsigned short* __restrict__ zb16,
          const int* __restrict__ ei, const float* __restrict__ ew,
          int* __restrict__ cur, int* __restrict__ csrs, float* __restrict__ csrw)
{
    const int j = threadIdx.x;
    if (blockIdx.x >= NB) {               // ---- CSR scatter ----
        int e = (blockIdx.x - NB) * 256 + j;
        unsigned long long bal = __ballot(ei[2 * e + 1] != 0);
        int m = (bal != 0ull) ? 1 : 0;
        int d = edge_dst(ei, m, e);
        int pos = atomicAdd(&cur[d], 1);
        csrs[pos] = edge_src(ei, m, e);
        csrw[pos] = ew[e];
        return;
    }
    // ---- z = leaky(BN(h)) -> bf16 stream ----
    __shared__ float scs[64], shs[64];
    const int b = blockIdx.x;
    if (j < 64)        scs[j] = stats[128 + j];
    else if (j < 128)  shs[j - 64] = stats[192 + (j - 64)];
    __syncthreads();
    const float4* hb = (const float4*)(h_in + (size_t)b * NTC);
    float4 a = hb[2 * j], c4 = hb[2 * j + 1];     // elems 8j..8j+7 (t*64+c order)
    const int c0 = (j * 8) & 63;
    float z0 = a.x  * scs[c0+0] + shs[c0+0];
    float z1 = a.y  * scs[c0+1] + shs[c0+1];
    float z2 = a.z  * scs[c0+2] + shs[c0+2];
    float z3 = a.w  * scs[c0+3] + shs[c0+3];
    float z4 = c4.x * scs[c0+4] + shs[c0+4];
    float z5 = c4.y * scs[c0+5] + shs[c0+5];
    float z6 = c4.z * scs[c0+6] + shs[c0+6];
    float z7 = c4.w * scs[c0+7] + shs[c0+7];
    z0 = (z0 >= 0.f) ? z0 : SLOPE_F * z0;  z1 = (z1 >= 0.f) ? z1 : SLOPE_F * z1;
    z2 = (z2 >= 0.f) ? z2 : SLOPE_F * z2;  z3 = (z3 >= 0.f) ? z3 : SLOPE_F * z3;
    z4 = (z4 >= 0.f) ? z4 : SLOPE_F * z4;  z5 = (z5 >= 0.f) ? z5 : SLOPE_F * z5;
    z6 = (z6 >= 0.f) ? z6 : SLOPE_F * z6;  z7 = (z7 >= 0.f) ? z7 : SLOPE_F * z7;
    uint4 q;
    q.x = pk2(z0, z1); q.y = pk2(z2, z3); q.z = pk2(z4, z5); q.w = pk2(z6, z7);
    ((uint4*)(zb16 + (size_t)b * NTC))[j] = q;
}

// ---------------- hop 1: TWO-PASS gather z (bf16) -> p1 int16 --------------
// Pass p covers row columns [p*1024, (p+1)*1024) (2KB half-rows): per-pass
// gather working set 8.4 -> 4.2 MB ~ per-XCD 4MB L2, so the 2nd+ touch per
// XCD hits L2 instead of thrashing to L3. Thread j owns elems
// {p*1024+4j..+3}; uint2 loads (512B/wave-instr, coalesced).
__global__ __launch_bounds__(256, 6)
void k_hop1(const unsigned short* __restrict__ p_in, const int* __restrict__ rowp,
            const int* __restrict__ csrs, const float* __restrict__ csrw,
            unsigned short* __restrict__ p1q, float* __restrict__ p1scl)
{
    __shared__ float mred[4];
    const int d = blockIdx.x, j = threadIdx.x;
    const int beg = rowp[d], end = rowp[d + 1];
    float acc[2][4];
#pragma unroll
    for (int p = 0; p < 2; ++p)
#pragma unroll
        for (int r = 0; r < 4; ++r) acc[p][r] = 0.f;

#pragma unroll
    for (int p = 0; p < 2; ++p) {
        const unsigned short* __restrict__ pbase = p_in + p * 1024;
        float* ac = acc[p];
        int e = beg;
        for (; e + 8 <= end; e += 8) {            // 8 gathers in flight (8B each)
            int   s0 = csrs[e],   s1 = csrs[e+1], s2 = csrs[e+2], s3 = csrs[e+3];
            int   s4 = csrs[e+4], s5 = csrs[e+5], s6 = csrs[e+6], s7 = csrs[e+7];
            float w0 = csrw[e],   w1 = csrw[e+1], w2 = csrw[e+2], w3 = csrw[e+3];
            float w4 = csrw[e+4], w5 = csrw[e+5], w6 = csrw[e+6], w7 = csrw[e+7];
            uint2 v0 = ((const uint2*)(pbase + (size_t)s0 * NTC))[j];
            uint2 v1 = ((const uint2*)(pbase + (size_t)s1 * NTC))[j];
            uint2 v2 = ((const uint2*)(pbase + (size_t)s2 * NTC))[j];
            uint2 v3 = ((const uint2*)(pbase + (size_t)s3 * NTC))[j];
            uint2 v4 = ((const uint2*)(pbase + (size_t)s4 * NTC))[j];
            uint2 v5 = ((const uint2*)(pbase + (size_t)s5 * NTC))[j];
            uint2 v6 = ((const uint2*)(pbase + (size_t)s6 * NTC))[j];
            uint2 v7 = ((const uint2*)(pbase + (size_t)s7 * NTC))[j];
            accv4(ac, v0, w0); accv4(ac, v1, w1);
            accv4(ac, v2, w2); accv4(ac, v3, w3);
            accv4(ac, v4, w4); accv4(ac, v5, w5);
            accv4(ac, v6, w6); accv4(ac, v7, w7);
        }
        for (; e + 2 <= end; e += 2) {
            int s0 = csrs[e],  s1 = csrs[e+1];
            float w0 = csrw[e], w1 = csrw[e+1];
            uint2 v0 = ((const uint2*)(pbase + (size_t)s0 * NTC))[j];
            uint2 v1 = ((const uint2*)(pbase + (size_t)s1 * NTC))[j];
            accv4(ac, v0, w0); accv4(ac, v1, w1);
        }
        if (e < end) {
            int s0 = csrs[e];
            float w0 = csrw[e];
            uint2 v0 = ((const uint2*)(pbase + (size_t)s0 * NTC))[j];
            accv4(ac, v0, w0);
        }
    }

    // ---- per-node max|p1| reduce (for int16 scale) ----
    const int lane = j & 63, w = j >> 6;
    float m = 0.f;
#pragma unroll
    for (int p = 0; p < 2; ++p)
#pragma unroll
        for (int r = 0; r < 4; ++r) m = fmaxf(m, fabsf(acc[p][r]));
#pragma unroll
    for (int off = 32; off > 0; off >>= 1)
        m = fmaxf(m, __shfl_down(m, off, 64));
    if (lane == 0) mred[w] = m;
    __syncthreads();
    const float mv = fmaxf(fmaxf(mred[0], mred[1]), fmaxf(mred[2], mred[3]));
    const float inv = (mv > 0.f) ? (32767.f / mv) : 0.f;
    if (j == 0) p1scl[d] = mv * (1.f / 32767.f);

    // int16 p1 store: pass p's elems land at uint2 slot p*256+j (byte p*2048+8j)
    uint2* po = (uint2*)(p1q + (size_t)d * NTC);
#pragma unroll
    for (int p = 0; p < 2; ++p) {
        uint2 qv;
        qv.x = pkq2(acc[p][0], acc[p][1], inv);
        qv.y = pkq2(acc[p][2], acc[p][3], inv);
        po[p * 256 + j] = qv;
    }
}

// ---------------- hop 2: TWO-PASS int16 gather + FULL fused epilogue -------
// out = h + tb + z@W0 + p1@W1 + (p2H@W2H + p2H@W2L + p2L@W2H)  -- pure store.
__global__ __launch_bounds__(256, 4)
void k_hop2(const unsigned short* __restrict__ p1q, const float* __restrict__ p1scl,
            const unsigned short* __restrict__ zb16, const float* __restrict__ h_in,
            const int* __restrict__ rowp, const int* __restrict__ csrs,
            const float* __restrict__ csrw,
            const unsigned short* __restrict__ twB,    // W0 @0, W1 @4096, W2hi @8192
            const unsigned short* __restrict__ twB2lo, // W2 lo, B-layout
            const float* __restrict__ tb,
            float* __restrict__ out)
{
    __shared__ __align__(16) unsigned short zA[32 * 64];   // bf16 z[d]
    __shared__ __align__(16) unsigned short pA[32 * 64];   // bf16 p1[d] (dequant)
    __shared__ __align__(16) unsigned short pH[32 * 64];   // bf16 p2 hi
    __shared__ __align__(16) unsigned short pL[32 * 64];   // bf16 p2 lo
    __shared__ float hl[32 * 65];                          // fp32 h residual
    const int d = blockIdx.x, j = threadIdx.x;

    {   // stage own rows: z (bf16 copy), h (fp32), p1 (dequant int16 -> bf16)
        uint4 zv = ((const uint4*)(zb16 + (size_t)d * NTC))[j];
        ((uint4*)zA)[j] = zv;
        const float4* hb4 = (const float4*)(h_in + (size_t)d * NTC);
        float4 h0 = hb4[2 * j], h1 = hb4[2 * j + 1];
        int tt = j >> 3, c0 = (j & 7) * 8;
        float* q = &hl[tt * 65 + c0];
        q[0] = h0.x; q[1] = h0.y; q[2] = h0.z; q[3] = h0.w;
        q[4] = h1.x; q[5] = h1.y; q[6] = h1.z; q[7] = h1.w;
        uint4 pq = ((const uint4*)(p1q + (size_t)d * NTC))[j];
        const float scl = p1scl[d];
        uint4 pb;
        pb.x = pk2(scl * (float)(short)(pq.x & 0xFFFFu), scl * (float)(short)(pq.x >> 16));
        pb.y = pk2(scl * (float)(short)(pq.y & 0xFFFFu), scl * (float)(short)(pq.y >> 16));
        pb.z = pk2(scl * (float)(short)(pq.z & 0xFFFFu), scl * (float)(short)(pq.z >> 16));
        pb.w = pk2(scl * (float)(short)(pq.w & 0xFFFFu), scl * (float)(short)(pq.w >> 16));
        ((uint4*)pA)[j] = pb;
    }

    const int beg = rowp[d], end = rowp[d + 1];
    float acc[2][4];
#pragma unroll
    for (int p = 0; p < 2; ++p)
#pragma unroll
        for (int r = 0; r < 4; ++r) acc[p][r] = 0.f;

#pragma unroll
    for (int p = 0; p < 2; ++p) {
        const unsigned short* __restrict__ pbase = p1q + p * 1024;
        float* ac = acc[p];
        int e = beg;
        for (; e + 8 <= end; e += 8) {            // 8 gathers in flight (8B each)
            int   s0 = csrs[e],   s1 = csrs[e+1], s2 = csrs[e+2], s3 = csrs[e+3];
            int   s4 = csrs[e+4], s5 = csrs[e+5], s6 = csrs[e+6], s7 = csrs[e+7];
            float w0 = csrw[e]   * p1scl[s0];
            float w1 = csrw[e+1] * p1scl[s1];
            float w2 = csrw[e+2] * p1scl[s2];
            float w3 = csrw[e+3] * p1scl[s3];
            float w4 = csrw[e+4] * p1scl[s4];
            float w5 = csrw[e+5] * p1scl[s5];
            float w6 = csrw[e+6] * p1scl[s6];
            float w7 = csrw[e+7] * p1scl[s7];
            uint2 v0 = ((const uint2*)(pbase + (size_t)s0 * NTC))[j];
            uint2 v1 = ((const uint2*)(pbase + (size_t)s1 * NTC))[j];
            uint2 v2 = ((const uint2*)(pbase + (size_t)s2 * NTC))[j];
            uint2 v3 = ((const uint2*)(pbase + (size_t)s3 * NTC))[j];
            uint2 v4 = ((const uint2*)(pbase + (size_t)s4 * NTC))[j];
            uint2 v5 = ((const uint2*)(pbase + (size_t)s5 * NTC))[j];
            uint2 v6 = ((const uint2*)(pbase + (size_t)s6 * NTC))[j];
            uint2 v7 = ((const uint2*)(pbase + (size_t)s7 * NTC))[j];
            acci16_4(ac, v0, w0); acci16_4(ac, v1, w1);
            acci16_4(ac, v2, w2); acci16_4(ac, v3, w3);
            acci16_4(ac, v4, w4); acci16_4(ac, v5, w5);
            acci16_4(ac, v6, w6); acci16_4(ac, v7, w7);
        }
        for (; e + 2 <= end; e += 2) {
            int s0 = csrs[e],  s1 = csrs[e+1];
            float w0 = csrw[e]   * p1scl[s0];
            float w1 = csrw[e+1] * p1scl[s1];
            uint2 v0 = ((const uint2*)(pbase + (size_t)s0 * NTC))[j];
            uint2 v1 = ((const uint2*)(pbase + (size_t)s1 * NTC))[j];
            acci16_4(ac, v0, w0); acci16_4(ac, v1, w1);
        }
        if (e < end) {
            int s0 = csrs[e];
            float w0 = csrw[e] * p1scl[s0];
            uint2 v0 = ((const uint2*)(pbase + (size_t)s0 * NTC))[j];
            acci16_4(ac, v0, w0);
        }
    }
    {   // hi/lo split-pack p2 into LDS; pass p elems -> uint2 slot p*256+j
        uint2* ph2 = (uint2*)pH;
        uint2* pl2 = (uint2*)pL;
#pragma unroll
        for (int p = 0; p < 2; ++p) {
            uint2 qh, ql;
            spl2(acc[p][0], acc[p][1], qh.x, ql.x);
            spl2(acc[p][2], acc[p][3], qh.y, ql.y);
            ph2[p * 256 + j] = qh;
            pl2[p * 256 + j] = ql;
        }
    }
    __syncthreads();

    const int lane = j & 63, w = j >> 6;
    const int n16 = lane & 15, quad = lane >> 4;
    const int g = w * 16 + n16;

    f32x4 d0 = {0.f, 0.f, 0.f, 0.f};
    f32x4 d1 = {0.f, 0.f, 0.f, 0.f};
    {   // z @ W0
        bf16x8 a00 = *(const bf16x8*)(zA + (n16)      * 64 +      quad * 8);
        bf16x8 a01 = *(const bf16x8*)(zA + (n16)      * 64 + 32 + quad * 8);
        bf16x8 a10 = *(const bf16x8*)(zA + (16 + n16) * 64 +      quad * 8);
        bf16x8 a11 = *(const bf16x8*)(zA + (16 + n16) * 64 + 32 + quad * 8);
        bf16x8 b0  = *(const bf16x8*)(twB + g * 64 +      quad * 8);
        bf16x8 b1  = *(const bf16x8*)(twB + g * 64 + 32 + quad * 8);
        d0 = __builtin_amdgcn_mfma_f32_16x16x32_bf16(a00, b0, d0, 0, 0, 0);
        d0 = __builtin_amdgcn_mfma_f32_16x16x32_bf16(a01, b1, d0, 0, 0, 0);
        d1 = __builtin_amdgcn_mfma_f32_16x16x32_bf16(a10, b0, d1, 0, 0, 0);
        d1 = __builtin_amdgcn_mfma_f32_16x16x32_bf16(a11, b1, d1, 0, 0, 0);
    }
    {   // p1 @ W1
        bf16x8 a00 = *(const bf16x8*)(pA + (n16)      * 64 +      quad * 8);
        bf16x8 a01 = *(const bf16x8*)(pA + (n16)      * 64 + 32 + quad * 8);
        bf16x8 a10 = *(const bf16x8*)(pA + (16 + n16) * 64 +      quad * 8);
        bf16x8 a11 = *(const bf16x8*)(pA + (16 + n16) * 64 + 32 + quad * 8);
        bf16x8 b0  = *(const bf16x8*)(twB + 4096 + g * 64 +      quad * 8);
        bf16x8 b1  = *(const bf16x8*)(twB + 4096 + g * 64 + 32 + quad * 8);
        d0 = __builtin_amdgcn_mfma_f32_16x16x32_bf16(a00, b0, d0, 0, 0, 0);
        d0 = __builtin_amdgcn_mfma_f32_16x16x32_bf16(a01, b1, d0, 0, 0, 0);
        d1 = __builtin_amdgcn_mfma_f32_16x16x32_bf16(a10, b0, d1, 0, 0, 0);
        d1 = __builtin_amdgcn_mfma_f32_16x16x32_bf16(a11, b1, d1, 0, 0, 0);
    }
    {   // p2 split @ W2: hi@hi + hi@lo + lo@hi
        bf16x8 ah00 = *(const bf16x8*)(pH + (n16)      * 64 +      quad * 8);
        bf16x8 ah01 = *(const bf16x8*)(pH + (n16)      * 64 + 32 + quad * 8);
        bf16x8 ah10 = *(const bf16x8*)(pH + (16 + n16) * 64 +      quad * 8);
        bf16x8 ah11 = *(const bf16x8*)(pH + (16 + n16) * 64 + 32 + quad * 8);
        bf16x8 b0h  = *(const bf16x8*)(twB + 8192 + g * 64 +      quad * 8);
        bf16x8 b1h  = *(const bf16x8*)(twB + 8192 + g * 64 + 32 + quad * 8);
        d0 = __builtin_amdgcn_mfma_f32_16x16x32_bf16(ah00, b0h, d0, 0, 0, 0);
        d0 = __builtin_amdgcn_mfma_f32_16x16x32_bf16(ah01, b1h, d0, 0, 0, 0);
        d1 = __builtin_amdgcn_mfma_f32_16x16x32_bf16(ah10, b0h, d1, 0, 0, 0);
        d1 = __builtin_amdgcn_mfma_f32_16x16x32_bf16(ah11, b1h, d1, 0, 0, 0);
        bf16x8 b0l  = *(const bf16x8*)(twB2lo + g * 64 +      quad * 8);
        bf16x8 b1l  = *(const bf16x8*)(twB2lo + g * 64 + 32 + quad * 8);
        d0 = __builtin_amdgcn_mfma_f32_16x16x32_bf16(ah00, b0l, d0, 0, 0, 0);
        d0 = __builtin_amdgcn_mfma_f32_16x16x32_bf16(ah01, b1l, d0, 0, 0, 0);
        d1 = __builtin_amdgcn_mfma_f32_16x16x32_bf16(ah10, b0l, d1, 0, 0, 0);
        d1 = __builtin_amdgcn_mfma_f32_16x16x32_bf16(ah11, b1l, d1, 0, 0, 0);
        bf16x8 al00 = *(const bf16x8*)(pL + (n16)      * 64 +      quad * 8);
        bf16x8 al01 = *(const bf16x8*)(pL + (n16)      * 64 + 32 + quad * 8);
        bf16x8 al10 = *(const bf16x8*)(pL + (16 + n16) * 64 +      quad * 8);
        bf16x8 al11 = *(const bf16x8*)(pL + (16 + n16) * 64 + 32 + quad * 8);
        d0 = __builtin_amdgcn_mfma_f32_16x16x32_bf16(al00, b0h, d0, 0, 0, 0);
        d0 = __builtin_amdgcn_mfma_f32_16x16x32_bf16(al01, b1h, d0, 0, 0, 0);
        d1 = __builtin_amdgcn_mfma_f32_16x16x32_bf16(al10, b0h, d1, 0, 0, 0);
        d1 = __builtin_amdgcn_mfma_f32_16x16x32_bf16(al11, b1h, d1, 0, 0, 0);
    }

    const float tbg = tb[g];
    float* ob = out + (size_t)d * NTC + g * 32;   // out[b][g][t], pure store
    {
        float4 v;                                  // mtile 0: t = quad*4..+3
        v.x = d0[0] + tbg + hl[(quad * 4 + 0) * 65 + g];
        v.y = d0[1] + tbg + hl[(quad * 4 + 1) * 65 + g];
        v.z = d0[2] + tbg + hl[(quad * 4 + 2) * 65 + g];
        v.w = d0[3] + tbg + hl[(quad * 4 + 3) * 65 + g];
        *(float4*)(ob + quad * 4) = v;
    }
    {
        float4 v;                                  // mtile 1: t = 16+quad*4..+3
        v.x = d1[0] + tbg + hl[(16 + quad * 4 + 0) * 65 + g];
        v.y = d1[1] + tbg + hl[(16 + quad * 4 + 1) * 65 + g];
        v.z = d1[2] + tbg + hl[(16 + quad * 4 + 2) * 65 + g];
        v.w = d1[3] + tbg + hl[(16 + quad * 4 + 3) * 65 + g];
        *(float4*)(ob + 16 + quad * 4) = v;
    }
}

// ---------------- launch ----------------
// workspace floats:
//   [0, 4194304)          h_in [b][t][c] fp32
//   [4194304, 6291456)    p1q int16 [b][t][c] (ushort, 8MB)
//   [6291456, 6293504)    p1scl [b] fp32 (8KB)
//   [8388608, 10485760)   z_bf16 [b][t][c] (ushort, 8MB)
//   [10485760, +256)      stats (scale[64]@128, shift[64]@192)
//   [10486016, +6144)     wAb (bf16 conv A-layout, 24KB)
//   [10492160, +6144)     twB (bf16 tag W^T B-layout, 24KB; W0/W1/W2hi)
//   [10498304, +262144)   partials [b][128]
//   [10760448, ...)       ints: hist(2048) rowp(2049+pad) cur(2048)
//                               csrs(32768) csrw(32768)
//   [10832640, +2048)     twBlo (bf16 W2 split-lo B-layout, 8KB)
extern "C" void kernel_launch(void* const* d_in, const int* in_sizes, int n_in,
                              void* d_out, int out_size, void* d_ws, size_t ws_size,
                              hipStream_t stream)
{
    const float* x  = (const float*)d_in[0];
    const int*   ei = (const int*)  d_in[1];
    const float* ew = (const float*)d_in[2];
    const float* cw = (const float*)d_in[3];
    const float* cb = (const float*)d_in[4];
    const float* lg = (const float*)d_in[5];
    const float* lb = (const float*)d_in[6];
    const float* bg = (const float*)d_in[7];
    const float* bb = (const float*)d_in[8];
    const float* tw = (const float*)d_in[9];
    const float* tb = (const float*)d_in[10];
    float* out = (float*)d_out;
    float* ws  = (float*)d_ws;

    float*          h_in  = ws;
    unsigned short* p1q   = (unsigned short*)(ws + 4194304);
    float*          p1scl = ws + 6291456;
    unsigned short* zbf   = (unsigned short*)(ws + 8388608);
    float*          stats = ws + 10485760;
    unsigned short* wAb   = (unsigned short*)(ws + 10486016);
    unsigned short* twB   = (unsigned short*)(ws + 10492160);
    float*          parts = ws + 10498304;
    int*            ib    = (int*)(ws + 10760448);
    unsigned short* twBlo = (unsigned short*)(ws + 10832640);
    int*   hist  = ib;
    int*   rowp  = ib + 2048;
    int*   cur   = ib + 4100;
    int*   csrs  = ib + 6148;
    float* csrw  = (float*)(ib + 38916);

    k_pre  <<<112,      256, 0, stream>>>(hist, cw, wAb, tw, twB, twBlo);
    k_main <<<NB + 128, 256, 0, stream>>>(x, wAb, cb, lg, lb, h_in, parts, ei, hist);
    k_mid  <<<65,       256, 0, stream>>>(hist, rowp, cur, parts, bg, bb, stats);
    k_zs   <<<NB + 128, 256, 0, stream>>>(h_in, stats, zbf, ei, ew, cur, csrs, csrw);
    k_hop1 <<<NB,       256, 0, stream>>>(zbf, rowp, csrs, csrw, p1q, p1scl);
    k_hop2 <<<NB,       256, 0, stream>>>(p1q, p1scl, zbf, h_in, rowp, csrs, csrw,
                                          twB, twBlo, tb, out);
}

// Round 8
// 155.208 us; speedup vs baseline: 1.0419x; 1.0419x over previous
//
#include <hip/hip_runtime.h>
#include <cstddef>

// B=2048, C_IN=C_OUT=64, T=32, E=32768, K_HOPS=2, KSIZE=3
#define NB   2048
#define NE   32768
#define NTC  2048      // T*C elems per node
#define SLOPE_F 0.01f
#define EPS_F   1e-5f

typedef short bf16x8 __attribute__((ext_vector_type(8)));
typedef float f32x4  __attribute__((ext_vector_type(4)));

// bf16 helpers (manual, RNE pack)
__device__ __forceinline__ unsigned short f2bf(float f) {
    unsigned u = __builtin_bit_cast(unsigned, f);
    u += 0x7FFF + ((u >> 16) & 1);
    return (unsigned short)(u >> 16);
}
__device__ __forceinline__ float bflo(unsigned v) {
    return __builtin_bit_cast(float, v << 16);
}
__device__ __forceinline__ unsigned pk2(float lo, float hi) {
    return (unsigned)f2bf(lo) | ((unsigned)f2bf(hi) << 16);
}
// unpack-accumulate 8 int8 lanes of a uint2 into acc[0..7] (wt has scale folded)
__device__ __forceinline__ void acci8(float* acc, const uint2& v, float wt) {
    acc[0] += wt * (float)(signed char)(v.x);
    acc[1] += wt * (float)(signed char)(v.x >> 8);
    acc[2] += wt * (float)(signed char)(v.x >> 16);
    acc[3] += wt * (float)(signed char)(v.x >> 24);
    acc[4] += wt * (float)(signed char)(v.y);
    acc[5] += wt * (float)(signed char)(v.y >> 8);
    acc[6] += wt * (float)(signed char)(v.y >> 16);
    acc[7] += wt * (float)(signed char)(v.y >> 24);
}
// unpack-accumulate 8 int16 lanes of a uint4 into acc[0..7] (wt has scale folded)
__device__ __forceinline__ void acci16(float* acc, const uint4& v, float wt) {
    acc[0] += wt * (float)(short)(v.x & 0xFFFFu); acc[1] += wt * (float)(short)(v.x >> 16);
    acc[2] += wt * (float)(short)(v.y & 0xFFFFu); acc[3] += wt * (float)(short)(v.y >> 16);
    acc[4] += wt * (float)(short)(v.z & 0xFFFFu); acc[5] += wt * (float)(short)(v.z >> 16);
    acc[6] += wt * (float)(short)(v.w & 0xFFFFu); acc[7] += wt * (float)(short)(v.w >> 16);
}
__device__ __forceinline__ unsigned pkq2(float a, float b, float inv) {
    int qa = __float2int_rn(a * inv);
    int qb = __float2int_rn(b * inv);
    return ((unsigned)qa & 0xFFFFu) | ((unsigned)qb << 16);
}
__device__ __forceinline__ unsigned pkq8x4(float a, float b, float c, float d, float inv) {
    int qa = __float2int_rn(a * inv), qb = __float2int_rn(b * inv);
    int qc = __float2int_rn(c * inv), qd = __float2int_rn(d * inv);
    return ((unsigned)qa & 0xFFu) | (((unsigned)qb & 0xFFu) << 8) |
           (((unsigned)qc & 0xFFu) << 16) | (((unsigned)qd & 0xFFu) << 24);
}
// split f into bf16 hi + bf16 lo (lo = exact fp32 residual, then RNE to bf16)
__device__ __forceinline__ void spl2(float a, float b, unsigned& hw, unsigned& lw) {
    unsigned short ha = f2bf(a), hb = f2bf(b);
    float ra = a - bflo((unsigned)ha);
    float rb = b - bflo((unsigned)hb);
    hw = (unsigned)ha | ((unsigned)hb << 16);
    lw = (unsigned)f2bf(ra) | ((unsigned)f2bf(rb) << 16);
}

// ---------------- edge-index width handling (per-wave ballot detect) -------
// int64 layout: high words ei[2e+1] all 0 (ids < 2048). int32 layout:
// P(64 sampled ids all zero) = 2048^-64 ~ 0. Wave-local ballot decides.
__device__ __forceinline__ int edge_src(const int* ei, int m, int e) {
    return m ? ei[e] : ei[2 * e];
}
__device__ __forceinline__ int edge_dst(const int* ei, int m, int e) {
    return m ? ei[NE + e] : ei[2 * (NE + e)];
}

// ---------------- dispatch 1: zero hist + pack weights ---------------------
__global__ __launch_bounds__(256)
void k_pre(int* __restrict__ hist, const float* __restrict__ cw,
           unsigned short* __restrict__ wAb, const float* __restrict__ tw,
           unsigned short* __restrict__ twB, unsigned short* __restrict__ twBlo)
{
    int gid = blockIdx.x * 256 + threadIdx.x;
    if (gid < 2048) hist[gid] = 0;
    if (blockIdx.x < 48) {
        int idx = gid;                    // 0..12287
        int kk = idx >> 12, o = (idx >> 6) & 63, i = idx & 63;
        wAb[idx] = f2bf(cw[o * 192 + i * 3 + kk]);
    } else if (blockIdx.x < 96) {
        int idx = gid - 48 * 256;         // 0..12287
        int mm = idx >> 12, rem = idx & 4095;
        int g = rem >> 6, k = rem & 63;
        twB[idx] = f2bf(tw[mm * 4096 + k * 64 + g]);
    } else {                              // blocks 96..111: W2 split-lo
        int idx = gid - 96 * 256;         // 0..4095
        int g = idx >> 6, k = idx & 63;
        float v = tw[2 * 4096 + k * 64 + g];
        unsigned short hi = f2bf(v);
        twBlo[idx] = f2bf(v - bflo((unsigned)hi));
    }
}

// ---------------- dispatch 2: convln (blocks 0..2047) U hist (2048..2175) --
__global__ __launch_bounds__(256, 4)
void k_main(const float* __restrict__ x, const unsigned short* __restrict__ wAb,
            const float* __restrict__ cb, const float* __restrict__ lg,
            const float* __restrict__ lb, float* __restrict__ h_in,
            float* __restrict__ partials,
            const int* __restrict__ ei, int* __restrict__ hist)
{
    if (blockIdx.x >= NB) {               // ---- hist part (whole blocks) ----
        int e = (blockIdx.x - NB) * 256 + threadIdx.x;
        unsigned long long bal = __ballot(ei[2 * e + 1] != 0);
        int m = (bal != 0ull) ? 1 : 0;
        atomicAdd(&hist[edge_dst(ei, m, e)], 1);
        return;
    }
    __shared__ __align__(16) unsigned short xT[36 * 72];
    __shared__ float hT[32 * 65];
    __shared__ float red1[64], red2[64];
    __shared__ float wsum[8];
    __shared__ float bcast[2];

    const int b = blockIdx.x, j = threadIdx.x;
    const float* __restrict__ xg = x + (size_t)b * NTC;

    {   // stage x -> bf16 xT[t+2][i]; zero-pad rows 0,1,34,35
        unsigned* xTd = (unsigned*)xT;
        int t = j & 31, p = j >> 5;
#pragma unroll
        for (int r = 0; r < 4; ++r) {
            int i0 = (r * 8 + p) * 2;
            float v0 = xg[i0 * 32 + t];
            float v1 = xg[(i0 + 1) * 32 + t];
            xTd[(t + 2) * 36 + (i0 >> 1)] = pk2(v0, v1);
        }
        if (j < 72)       xTd[j] = 0u;
        else if (j < 144) xTd[1224 + (j - 72)] = 0u;   // rows 34,35
    }
    __syncthreads();

    const int lane = j & 63, w = j >> 6;
    const int n16 = lane & 15, quad = lane >> 4;

    bf16x8 afr[3][2];
#pragma unroll
    for (int kk = 0; kk < 3; ++kk)
#pragma unroll
        for (int s = 0; s < 2; ++s) {
            int off16 = (kk * 64 + w * 16 + n16) * 64 + s * 32 + quad * 8;
            afr[kk][s] = *(const bf16x8*)(wAb + off16);
        }

    f32x4 acc0 = {0.f, 0.f, 0.f, 0.f};
    f32x4 acc1 = {0.f, 0.f, 0.f, 0.f};
#pragma unroll
    for (int kk = 0; kk < 3; ++kk)
#pragma unroll
        for (int s = 0; s < 2; ++s) {
            bf16x8 b0 = *(const bf16x8*)(xT + (n16 + kk) * 72 + s * 32 + quad * 8);
            bf16x8 b1 = *(const bf16x8*)(xT + (16 + n16 + kk) * 72 + s * 32 + quad * 8);
            acc0 = __builtin_amdgcn_mfma_f32_16x16x32_bf16(afr[kk][s], b0, acc0, 0, 0, 0);
            acc1 = __builtin_amdgcn_mfma_f32_16x16x32_bf16(afr[kk][s], b1, acc1, 0, 0, 0);
        }

    float vals[2][4];
    float s1 = 0.f, s2 = 0.f;
#pragma unroll
    for (int r = 0; r < 4; ++r) {
        float cbv = cb[w * 16 + quad * 4 + r];
        float v0 = acc0[r] + cbv;
        float v1 = acc1[r] + cbv;
        v0 = (v0 >= 0.f) ? v0 : SLOPE_F * v0;
        v1 = (v1 >= 0.f) ? v1 : SLOPE_F * v1;
        vals[0][r] = v0; vals[1][r] = v1;
        s1 += v0 + v1; s2 += v0 * v0 + v1 * v1;
    }
#pragma unroll
    for (int off = 32; off > 0; off >>= 1) {
        s1 += __shfl_down(s1, off, 64);
        s2 += __shfl_down(s2, off, 64);
    }
    if (lane == 0) { wsum[w] = s1; wsum[4 + w] = s2; }
    __syncthreads();
    if (j == 0) {
        float S1 = wsum[0] + wsum[1] + wsum[2] + wsum[3];
        float S2 = wsum[4] + wsum[5] + wsum[6] + wsum[7];
        float mu  = S1 * (1.f / 2048.f);
        float var = S2 * (1.f / 2048.f) - mu * mu;
        bcast[0] = mu;
        bcast[1] = rsqrtf(var + EPS_F);
    }
    __syncthreads();
    const float mu = bcast[0], rs = bcast[1];
    float po1[4] = {0.f, 0.f, 0.f, 0.f}, po2[4] = {0.f, 0.f, 0.f, 0.f};
#pragma unroll
    for (int nt = 0; nt < 2; ++nt) {
        int t = nt * 16 + n16;
#pragma unroll
        for (int r = 0; r < 4; ++r) {
            int o = w * 16 + quad * 4 + r;
            float h = (vals[nt][r] - mu) * rs * lg[o * 32 + t] + lb[o * 32 + t];
            hT[t * 65 + o] = h;
            po1[r] += h; po2[r] += h * h;
        }
    }
#pragma unroll
    for (int off = 8; off > 0; off >>= 1) {
#pragma unroll
        for (int r = 0; r < 4; ++r) {
            po1[r] += __shfl_down(po1[r], off, 16);
            po2[r] += __shfl_down(po2[r], off, 16);
        }
    }
    if (n16 == 0) {
#pragma unroll
        for (int r = 0; r < 4; ++r) {
            int o = w * 16 + quad * 4 + r;
            red1[o] = po1[r];
            red2[o] = po2[r];
        }
    }
    __syncthreads();
    float* hb = h_in + (size_t)b * NTC;
#pragma unroll
    for (int r = 0; r < 8; ++r) {                  // coalesced h_in store
        int idx = j + r * 256;
        hb[idx] = hT[(idx >> 6) * 65 + (idx & 63)];
    }
    float* pb_ = partials + (size_t)b * 128;       // coalesced 512B store
    if (j < 64)       pb_[j] = red1[j];
    else if (j < 128) pb_[j] = red2[j - 64];
}

// ---------------- dispatch 3: scan (block 0) U bnred (blocks 1..64) --------
__global__ __launch_bounds__(256)
void k_mid(const int* __restrict__ hist, int* __restrict__ rowp,
           int* __restrict__ cur, const float* __restrict__ partials,
           const float* __restrict__ bg, const float* __restrict__ bb,
           float* __restrict__ stats)
{
    __shared__ int part[256];
    __shared__ float r1[4], r2[4];
    const int j = threadIdx.x;
    if (blockIdx.x == 0) {                // ---- CSR row-pointer scan ----
        int loc[8]; int s = 0;
#pragma unroll
        for (int r = 0; r < 8; ++r) { loc[r] = hist[j * 8 + r]; s += loc[r]; }
        part[j] = s;
        __syncthreads();
        for (int off = 1; off < 256; off <<= 1) {
            int v = (j >= off) ? part[j - off] : 0;
            __syncthreads();
            part[j] += v;
            __syncthreads();
        }
        int excl = part[j] - s;
#pragma unroll
        for (int r = 0; r < 8; ++r) {
            rowp[j * 8 + r] = excl;
            cur [j * 8 + r] = excl;
            excl += loc[r];
        }
        if (j == 255) rowp[2048] = excl;  // == NE
        return;
    }
    // ---- BN partial reduce, c = blockIdx.x - 1 ----
    const int c = blockIdx.x - 1;
    float s1 = 0.f, s2 = 0.f;
    for (int b = j; b < NB; b += 256) {
        const float* p = partials + (size_t)b * 128;
        s1 += p[c];
        s2 += p[64 + c];
    }
#pragma unroll
    for (int off = 32; off > 0; off >>= 1) {
        s1 += __shfl_down(s1, off, 64);
        s2 += __shfl_down(s2, off, 64);
    }
    if ((j & 63) == 0) { r1[j >> 6] = s1; r2[j >> 6] = s2; }
    __syncthreads();
    if (j == 0) {
        float S1 = r1[0] + r1[1] + r1[2] + r1[3];
        float S2 = r2[0] + r2[1] + r2[2] + r2[3];
        const float inv_n = 1.f / 65536.f;
        float mu  = S1 * inv_n;
        float var = S2 * inv_n - mu * mu;
        float rs  = rsqrtf(var + EPS_F);
        float sc  = bg[c] * rs;
        stats[128 + c] = sc;
        stats[192 + c] = bb[c] - mu * sc;
    }
}

// ---------------- dispatch 4: z=leaky(BN(h)) -> int8 U scat ----------------
// z stored as per-node-scaled int8 (eps <= max_row|z|/127 ~ 0.014 abs):
// halves hop1's gather bytes (67 -> 33.5 MB logical). Error feeding p1 is
// ~0.03 abs (p1~30) -- 4x tighter than the bf16-p1 config that failed, and
// subdominant to the bf16 rounding already in hop2's p1@W1 MFMA A-operand.
__global__ __launch_bounds__(256)
void k_zs(const float* __restrict__ h_in, const float* __restrict__ stats,
          signed char* __restrict__ zq8, float* __restrict__ zscl,
          const int* __restrict__ ei, const float* __restrict__ ew,
          int* __restrict__ cur, int* __restrict__ csrs, float* __restrict__ csrw)
{
    const int j = threadIdx.x;
    if (blockIdx.x >= NB) {               // ---- CSR scatter ----
        int e = (blockIdx.x - NB) * 256 + j;
        unsigned long long bal = __ballot(ei[2 * e + 1] != 0);
        int m = (bal != 0ull) ? 1 : 0;
        int d = edge_dst(ei, m, e);
        int pos = atomicAdd(&cur[d], 1);
        csrs[pos] = edge_src(ei, m, e);
        csrw[pos] = ew[e];
        return;
    }
    __shared__ float scs[64], shs[64];
    __shared__ float mred[4];
    const int b = blockIdx.x;
    if (j < 64)        scs[j] = stats[128 + j];
    else if (j < 128)  shs[j - 64] = stats[192 + (j - 64)];
    __syncthreads();
    const float4* hb = (const float4*)(h_in + (size_t)b * NTC);
    float4 a = hb[2 * j], c4 = hb[2 * j + 1];     // elems 8j..8j+7 (t*64+c order)
    const int c0 = (j * 8) & 63;
    float z0 = a.x  * scs[c0+0] + shs[c0+0];
    float z1 = a.y  * scs[c0+1] + shs[c0+1];
    float z2 = a.z  * scs[c0+2] + shs[c0+2];
    float z3 = a.w  * scs[c0+3] + shs[c0+3];
    float z4 = c4.x * scs[c0+4] + shs[c0+4];
    float z5 = c4.y * scs[c0+5] + shs[c0+5];
    float z6 = c4.z * scs[c0+6] + shs[c0+6];
    float z7 = c4.w * scs[c0+7] + shs[c0+7];
    z0 = (z0 >= 0.f) ? z0 : SLOPE_F * z0;  z1 = (z1 >= 0.f) ? z1 : SLOPE_F * z1;
    z2 = (z2 >= 0.f) ? z2 : SLOPE_F * z2;  z3 = (z3 >= 0.f) ? z3 : SLOPE_F * z3;
    z4 = (z4 >= 0.f) ? z4 : SLOPE_F * z4;  z5 = (z5 >= 0.f) ? z5 : SLOPE_F * z5;
    z6 = (z6 >= 0.f) ? z6 : SLOPE_F * z6;  z7 = (z7 >= 0.f) ? z7 : SLOPE_F * z7;

    // ---- per-node max|z| reduce -> int8 scale ----
    const int lane = j & 63, w = j >> 6;
    float m = fmaxf(fmaxf(fmaxf(fabsf(z0), fabsf(z1)), fmaxf(fabsf(z2), fabsf(z3))),
                    fmaxf(fmaxf(fabsf(z4), fabsf(z5)), fmaxf(fabsf(z6), fabsf(z7))));
#pragma unroll
    for (int off = 32; off > 0; off >>= 1)
        m = fmaxf(m, __shfl_down(m, off, 64));
    if (lane == 0) mred[w] = m;
    __syncthreads();
    const float mv = fmaxf(fmaxf(mred[0], mred[1]), fmaxf(mred[2], mred[3]));
    const float inv = (mv > 0.f) ? (127.f / mv) : 0.f;
    if (j == 0) zscl[b] = mv * (1.f / 127.f);

    uint2 q;
    q.x = pkq8x4(z0, z1, z2, z3, inv);
    q.y = pkq8x4(z4, z5, z6, z7, inv);
    ((uint2*)(zq8 + (size_t)b * NTC))[j] = q;     // thread j owns bytes 8j..8j+7
}

// ---------------- hop 1: PURE int8 gather z -> p1 int16 --------------------
__global__ __launch_bounds__(256, 6)
void k_hop1(const signed char* __restrict__ zq8, const float* __restrict__ zscl,
            const int* __restrict__ rowp, const int* __restrict__ csrs,
            const float* __restrict__ csrw,
            unsigned short* __restrict__ p1q, float* __restrict__ p1scl)
{
    __shared__ float mred[4];
    const int d = blockIdx.x, j = threadIdx.x;
    const int beg = rowp[d], end = rowp[d + 1];
    float acc[8];
#pragma unroll
    for (int r = 0; r < 8; ++r) acc[r] = 0.f;
    int e = beg;
    for (; e + 8 <= end; e += 8) {                // 8 gathers in flight (8B each)
        int   s0 = csrs[e],   s1 = csrs[e+1], s2 = csrs[e+2], s3 = csrs[e+3];
        int   s4 = csrs[e+4], s5 = csrs[e+5], s6 = csrs[e+6], s7 = csrs[e+7];
        float w0 = csrw[e]   * zscl[s0];
        float w1 = csrw[e+1] * zscl[s1];
        float w2 = csrw[e+2] * zscl[s2];
        float w3 = csrw[e+3] * zscl[s3];
        float w4 = csrw[e+4] * zscl[s4];
        float w5 = csrw[e+5] * zscl[s5];
        float w6 = csrw[e+6] * zscl[s6];
        float w7 = csrw[e+7] * zscl[s7];
        uint2 v0 = ((const uint2*)(zq8 + (size_t)s0 * NTC))[j];
        uint2 v1 = ((const uint2*)(zq8 + (size_t)s1 * NTC))[j];
        uint2 v2 = ((const uint2*)(zq8 + (size_t)s2 * NTC))[j];
        uint2 v3 = ((const uint2*)(zq8 + (size_t)s3 * NTC))[j];
        uint2 v4 = ((const uint2*)(zq8 + (size_t)s4 * NTC))[j];
        uint2 v5 = ((const uint2*)(zq8 + (size_t)s5 * NTC))[j];
        uint2 v6 = ((const uint2*)(zq8 + (size_t)s6 * NTC))[j];
        uint2 v7 = ((const uint2*)(zq8 + (size_t)s7 * NTC))[j];
        acci8(acc, v0, w0); acci8(acc, v1, w1);
        acci8(acc, v2, w2); acci8(acc, v3, w3);
        acci8(acc, v4, w4); acci8(acc, v5, w5);
        acci8(acc, v6, w6); acci8(acc, v7, w7);
    }
    for (; e + 2 <= end; e += 2) {
        int s0 = csrs[e],  s1 = csrs[e+1];
        float w0 = csrw[e]   * zscl[s0];
        float w1 = csrw[e+1] * zscl[s1];
        uint2 v0 = ((const uint2*)(zq8 + (size_t)s0 * NTC))[j];
        uint2 v1 = ((const uint2*)(zq8 + (size_t)s1 * NTC))[j];
        acci8(acc, v0, w0); acci8(acc, v1, w1);
    }
    if (e < end) {
        int s0 = csrs[e];
        float w0 = csrw[e] * zscl[s0];
        uint2 v0 = ((const uint2*)(zq8 + (size_t)s0 * NTC))[j];
        acci8(acc, v0, w0);
    }

    // ---- per-node max|p1| reduce (for int16 scale) ----
    const int lane = j & 63, w = j >> 6;
    float m = 0.f;
#pragma unroll
    for (int r = 0; r < 8; ++r) m = fmaxf(m, fabsf(acc[r]));
#pragma unroll
    for (int off = 32; off > 0; off >>= 1)
        m = fmaxf(m, __shfl_down(m, off, 64));
    if (lane == 0) mred[w] = m;
    __syncthreads();
    const float mv = fmaxf(fmaxf(mred[0], mred[1]), fmaxf(mred[2], mred[3]));
    const float inv = (mv > 0.f) ? (32767.f / mv) : 0.f;
    if (j == 0) p1scl[d] = mv * (1.f / 32767.f);

    // int16 p1 store: thread j owns elems 8j..8j+7 of [t][c] row-major
    uint4 qv;
    qv.x = pkq2(acc[0], acc[1], inv);
    qv.y = pkq2(acc[2], acc[3], inv);
    qv.z = pkq2(acc[4], acc[5], inv);
    qv.w = pkq2(acc[6], acc[7], inv);
    ((uint4*)(p1q + (size_t)d * NTC))[j] = qv;
}

// ---------------- hop 2: int16 gather + FULL fused epilogue ----------------
// out = h + tb + z@W0 + p1@W1 + (p2H@W2H + p2H@W2L + p2L@W2H)  -- pure store.
__global__ __launch_bounds__(256, 4)
void k_hop2(const unsigned short* __restrict__ p1q, const float* __restrict__ p1scl,
            const signed char* __restrict__ zq8, const float* __restrict__ zscl,
            const float* __restrict__ h_in,
            const int* __restrict__ rowp, const int* __restrict__ csrs,
            const float* __restrict__ csrw,
            const unsigned short* __restrict__ twB,    // W0 @0, W1 @4096, W2hi @8192
            const unsigned short* __restrict__ twB2lo, // W2 lo, B-layout
            const float* __restrict__ tb,
            float* __restrict__ out)
{
    __shared__ __align__(16) unsigned short zA[32 * 64];   // bf16 z[d] (dequant)
    __shared__ __align__(16) unsigned short pA[32 * 64];   // bf16 p1[d] (dequant)
    __shared__ __align__(16) unsigned short pH[32 * 64];   // bf16 p2 hi
    __shared__ __align__(16) unsigned short pL[32 * 64];   // bf16 p2 lo
    __shared__ float hl[32 * 65];                          // fp32 h residual
    const int d = blockIdx.x, j = threadIdx.x;

    {   // stage own rows: z (dequant int8->bf16), h (fp32), p1 (dequant int16->bf16)
        uint2 zq = ((const uint2*)(zq8 + (size_t)d * NTC))[j];
        const float zs = zscl[d];
        uint4 zb;
        zb.x = pk2(zs * (float)(signed char)(zq.x),       zs * (float)(signed char)(zq.x >> 8));
        zb.y = pk2(zs * (float)(signed char)(zq.x >> 16), zs * (float)(signed char)(zq.x >> 24));
        zb.z = pk2(zs * (float)(signed char)(zq.y),       zs * (float)(signed char)(zq.y >> 8));
        zb.w = pk2(zs * (float)(signed char)(zq.y >> 16), zs * (float)(signed char)(zq.y >> 24));
        ((uint4*)zA)[j] = zb;
        const float4* hb4 = (const float4*)(h_in + (size_t)d * NTC);
        float4 h0 = hb4[2 * j], h1 = hb4[2 * j + 1];
        int tt = j >> 3, c0 = (j & 7) * 8;
        float* q = &hl[tt * 65 + c0];
        q[0] = h0.x; q[1] = h0.y; q[2] = h0.z; q[3] = h0.w;
        q[4] = h1.x; q[5] = h1.y; q[6] = h1.z; q[7] = h1.w;
        uint4 pq = ((const uint4*)(p1q + (size_t)d * NTC))[j];
        const float scl = p1scl[d];
        uint4 pb;
        pb.x = pk2(scl * (float)(short)(pq.x & 0xFFFFu), scl * (float)(short)(pq.x >> 16));
        pb.y = pk2(scl * (float)(short)(pq.y & 0xFFFFu), scl * (float)(short)(pq.y >> 16));
        pb.z = pk2(scl * (float)(short)(pq.z & 0xFFFFu), scl * (float)(short)(pq.z >> 16));
        pb.w = pk2(scl * (float)(short)(pq.w & 0xFFFFu), scl * (float)(short)(pq.w >> 16));
        ((uint4*)pA)[j] = pb;
    }

    const int beg = rowp[d], end = rowp[d + 1];
    float acc[8];
#pragma unroll
    for (int r = 0; r < 8; ++r) acc[r] = 0.f;
    int e = beg;
    for (; e + 8 <= end; e += 8) {                // 8 gathers in flight (16B each)
        int   s0 = csrs[e],   s1 = csrs[e+1], s2 = csrs[e+2], s3 = csrs[e+3];
        int   s4 = csrs[e+4], s5 = csrs[e+5], s6 = csrs[e+6], s7 = csrs[e+7];
        float w0 = csrw[e]   * p1scl[s0];
        float w1 = csrw[e+1] * p1scl[s1];
        float w2 = csrw[e+2] * p1scl[s2];
        float w3 = csrw[e+3] * p1scl[s3];
        float w4 = csrw[e+4] * p1scl[s4];
        float w5 = csrw[e+5] * p1scl[s5];
        float w6 = csrw[e+6] * p1scl[s6];
        float w7 = csrw[e+7] * p1scl[s7];
        uint4 v0 = ((const uint4*)(p1q + (size_t)s0 * NTC))[j];
        uint4 v1 = ((const uint4*)(p1q + (size_t)s1 * NTC))[j];
        uint4 v2 = ((const uint4*)(p1q + (size_t)s2 * NTC))[j];
        uint4 v3 = ((const uint4*)(p1q + (size_t)s3 * NTC))[j];
        uint4 v4 = ((const uint4*)(p1q + (size_t)s4 * NTC))[j];
        uint4 v5 = ((const uint4*)(p1q + (size_t)s5 * NTC))[j];
        uint4 v6 = ((const uint4*)(p1q + (size_t)s6 * NTC))[j];
        uint4 v7 = ((const uint4*)(p1q + (size_t)s7 * NTC))[j];
        acci16(acc, v0, w0); acci16(acc, v1, w1);
        acci16(acc, v2, w2); acci16(acc, v3, w3);
        acci16(acc, v4, w4); acci16(acc, v5, w5);
        acci16(acc, v6, w6); acci16(acc, v7, w7);
    }
    for (; e + 2 <= end; e += 2) {
        int s0 = csrs[e],  s1 = csrs[e+1];
        float w0 = csrw[e]   * p1scl[s0];
        float w1 = csrw[e+1] * p1scl[s1];
        uint4 v0 = ((const uint4*)(p1q + (size_t)s0 * NTC))[j];
        uint4 v1 = ((const uint4*)(p1q + (size_t)s1 * NTC))[j];
        acci16(acc, v0, w0); acci16(acc, v1, w1);
    }
    if (e < end) {
        int s0 = csrs[e];
        float w0 = csrw[e] * p1scl[s0];
        uint4 v0 = ((const uint4*)(p1q + (size_t)s0 * NTC))[j];
        acci16(acc, v0, w0);
    }
    {   // hi/lo split-pack p2 into LDS tiles (thread j owns elems 8j..8j+7, [t][c])
        uint4 qh, ql;
        spl2(acc[0], acc[1], qh.x, ql.x);
        spl2(acc[2], acc[3], qh.y, ql.y);
        spl2(acc[4], acc[5], qh.z, ql.z);
        spl2(acc[6], acc[7], qh.w, ql.w);
        ((uint4*)pH)[j] = qh;
        ((uint4*)pL)[j] = ql;
    }
    __syncthreads();

    const int lane = j & 63, w = j >> 6;
    const int n16 = lane & 15, quad = lane >> 4;
    const int g = w * 16 + n16;

    f32x4 d0 = {0.f, 0.f, 0.f, 0.f};
    f32x4 d1 = {0.f, 0.f, 0.f, 0.f};
    {   // z @ W0
        bf16x8 a00 = *(const bf16x8*)(zA + (n16)      * 64 +      quad * 8);
        bf16x8 a01 = *(const bf16x8*)(zA + (n16)      * 64 + 32 + quad * 8);
        bf16x8 a10 = *(const bf16x8*)(zA + (16 + n16) * 64 +      quad * 8);
        bf16x8 a11 = *(const bf16x8*)(zA + (16 + n16) * 64 + 32 + quad * 8);
        bf16x8 b0  = *(const bf16x8*)(twB + g * 64 +      quad * 8);
        bf16x8 b1  = *(const bf16x8*)(twB + g * 64 + 32 + quad * 8);
        d0 = __builtin_amdgcn_mfma_f32_16x16x32_bf16(a00, b0, d0, 0, 0, 0);
        d0 = __builtin_amdgcn_mfma_f32_16x16x32_bf16(a01, b1, d0, 0, 0, 0);
        d1 = __builtin_amdgcn_mfma_f32_16x16x32_bf16(a10, b0, d1, 0, 0, 0);
        d1 = __builtin_amdgcn_mfma_f32_16x16x32_bf16(a11, b1, d1, 0, 0, 0);
    }
    {   // p1 @ W1
        bf16x8 a00 = *(const bf16x8*)(pA + (n16)      * 64 +      quad * 8);
        bf16x8 a01 = *(const bf16x8*)(pA + (n16)      * 64 + 32 + quad * 8);
        bf16x8 a10 = *(const bf16x8*)(pA + (16 + n16) * 64 +      quad * 8);
        bf16x8 a11 = *(const bf16x8*)(pA + (16 + n16) * 64 + 32 + quad * 8);
        bf16x8 b0  = *(const bf16x8*)(twB + 4096 + g * 64 +      quad * 8);
        bf16x8 b1  = *(const bf16x8*)(twB + 4096 + g * 64 + 32 + quad * 8);
        d0 = __builtin_amdgcn_mfma_f32_16x16x32_bf16(a00, b0, d0, 0, 0, 0);
        d0 = __builtin_amdgcn_mfma_f32_16x16x32_bf16(a01, b1, d0, 0, 0, 0);
        d1 = __builtin_amdgcn_mfma_f32_16x16x32_bf16(a10, b0, d1, 0, 0, 0);
        d1 = __builtin_amdgcn_mfma_f32_16x16x32_bf16(a11, b1, d1, 0, 0, 0);
    }
    {   // p2 split @ W2: hi@hi + hi@lo + lo@hi
        bf16x8 ah00 = *(const bf16x8*)(pH + (n16)      * 64 +      quad * 8);
        bf16x8 ah01 = *(const bf16x8*)(pH + (n16)      * 64 + 32 + quad * 8);
        bf16x8 ah10 = *(const bf16x8*)(pH + (16 + n16) * 64 +      quad * 8);
        bf16x8 ah11 = *(const bf16x8*)(pH + (16 + n16) * 64 + 32 + quad * 8);
        bf16x8 b0h  = *(const bf16x8*)(twB + 8192 + g * 64 +      quad * 8);
        bf16x8 b1h  = *(const bf16x8*)(twB + 8192 + g * 64 + 32 + quad * 8);
        d0 = __builtin_amdgcn_mfma_f32_16x16x32_bf16(ah00, b0h, d0, 0, 0, 0);
        d0 = __builtin_amdgcn_mfma_f32_16x16x32_bf16(ah01, b1h, d0, 0, 0, 0);
        d1 = __builtin_amdgcn_mfma_f32_16x16x32_bf16(ah10, b0h, d1, 0, 0, 0);
        d1 = __builtin_amdgcn_mfma_f32_16x16x32_bf16(ah11, b1h, d1, 0, 0, 0);
        bf16x8 b0l  = *(const bf16x8*)(twB2lo + g * 64 +      quad * 8);
        bf16x8 b1l  = *(const bf16x8*)(twB2lo + g * 64 + 32 + quad * 8);
        d0 = __builtin_amdgcn_mfma_f32_16x16x32_bf16(ah00, b0l, d0, 0, 0, 0);
        d0 = __builtin_amdgcn_mfma_f32_16x16x32_bf16(ah01, b1l, d0, 0, 0, 0);
        d1 = __builtin_amdgcn_mfma_f32_16x16x32_bf16(ah10, b0l, d1, 0, 0, 0);
        d1 = __builtin_amdgcn_mfma_f32_16x16x32_bf16(ah11, b1l, d1, 0, 0, 0);
        bf16x8 al00 = *(const bf16x8*)(pL + (n16)      * 64 +      quad * 8);
        bf16x8 al01 = *(const bf16x8*)(pL + (n16)      * 64 + 32 + quad * 8);
        bf16x8 al10 = *(const bf16x8*)(pL + (16 + n16) * 64 +      quad * 8);
        bf16x8 al11 = *(const bf16x8*)(pL + (16 + n16) * 64 + 32 + quad * 8);
        d0 = __builtin_amdgcn_mfma_f32_16x16x32_bf16(al00, b0h, d0, 0, 0, 0);
        d0 = __builtin_amdgcn_mfma_f32_16x16x32_bf16(al01, b1h, d0, 0, 0, 0);
        d1 = __builtin_amdgcn_mfma_f32_16x16x32_bf16(al10, b0h, d1, 0, 0, 0);
        d1 = __builtin_amdgcn_mfma_f32_16x16x32_bf16(al11, b1h, d1, 0, 0, 0);
    }

    const float tbg = tb[g];
    float* ob = out + (size_t)d * NTC + g * 32;   // out[b][g][t], pure store
    {
        float4 v;                                  // mtile 0: t = quad*4..+3
        v.x = d0[0] + tbg + hl[(quad * 4 + 0) * 65 + g];
        v.y = d0[1] + tbg + hl[(quad * 4 + 1) * 65 + g];
        v.z = d0[2] + tbg + hl[(quad * 4 + 2) * 65 + g];
        v.w = d0[3] + tbg + hl[(quad * 4 + 3) * 65 + g];
        *(float4*)(ob + quad * 4) = v;
    }
    {
        float4 v;                                  // mtile 1: t = 16+quad*4..+3
        v.x = d1[0] + tbg + hl[(16 + quad * 4 + 0) * 65 + g];
        v.y = d1[1] + tbg + hl[(16 + quad * 4 + 1) * 65 + g];
        v.z = d1[2] + tbg + hl[(16 + quad * 4 + 2) * 65 + g];
        v.w = d1[3] + tbg + hl[(16 + quad * 4 + 3) * 65 + g];
        *(float4*)(ob + 16 + quad * 4) = v;
    }
}

// ---------------- launch ----------------
// workspace floats:
//   [0, 4194304)          h_in [b][t][c] fp32
//   [4194304, 6291456)    p1q int16 [b][t][c] (ushort, 8MB)
//   [6291456, 6293504)    p1scl [b] fp32 (8KB)
//   [6293504, 6295552)    zscl [b] fp32 (8KB)
//   [8388608, 9437184)    zq8 int8 [b][t][c] (char, 4.2MB)
//   [10485760, +256)      stats (scale[64]@128, shift[64]@192)
//   [10486016, +6144)     wAb (bf16 conv A-layout, 24KB)
//   [10492160, +6144)     twB (bf16 tag W^T B-layout, 24KB; W0/W1/W2hi)
//   [10498304, +262144)   partials [b][128]
//   [10760448, ...)       ints: hist(2048) rowp(2049+pad) cur(2048)
//                               csrs(32768) csrw(32768)
//   [10832640, +2048)     twBlo (bf16 W2 split-lo B-layout, 8KB)
extern "C" void kernel_launch(void* const* d_in, const int* in_sizes, int n_in,
                              void* d_out, int out_size, void* d_ws, size_t ws_size,
                              hipStream_t stream)
{
    const float* x  = (const float*)d_in[0];
    const int*   ei = (const int*)  d_in[1];
    const float* ew = (const float*)d_in[2];
    const float* cw = (const float*)d_in[3];
    const float* cb = (const float*)d_in[4];
    const float* lg = (const float*)d_in[5];
    const float* lb = (const float*)d_in[6];
    const float* bg = (const float*)d_in[7];
    const float* bb = (const float*)d_in[8];
    const float* tw = (const float*)d_in[9];
    const float* tb = (const float*)d_in[10];
    float* out = (float*)d_out;
    float* ws  = (float*)d_ws;

    float*          h_in  = ws;
    unsigned short* p1q   = (unsigned short*)(ws + 4194304);
    float*          p1scl = ws + 6291456;
    float*          zscl  = ws + 6293504;
    signed char*    zq8   = (signed char*)(ws + 8388608);
    float*          stats = ws + 10485760;
    unsigned short* wAb   = (unsigned short*)(ws + 10486016);
    unsigned short* twB   = (unsigned short*)(ws + 10492160);
    float*          parts = ws + 10498304;
    int*            ib    = (int*)(ws + 10760448);
    unsigned short* twBlo = (unsigned short*)(ws + 10832640);
    int*   hist  = ib;
    int*   rowp  = ib + 2048;
    int*   cur   = ib + 4100;
    int*   csrs  = ib + 6148;
    float* csrw  = (float*)(ib + 38916);

    k_pre  <<<112,      256, 0, stream>>>(hist, cw, wAb, tw, twB, twBlo);
    k_main <<<NB + 128, 256, 0, stream>>>(x, wAb, cb, lg, lb, h_in, parts, ei, hist);
    k_mid  <<<65,       256, 0, stream>>>(hist, rowp, cur, parts, bg, bb, stats);
    k_zs   <<<NB + 128, 256, 0, stream>>>(h_in, stats, zq8, zscl, ei, ew, cur, csrs, csrw);
    k_hop1 <<<NB,       256, 0, stream>>>(zq8, zscl, rowp, csrs, csrw, p1q, p1scl);
    k_hop2 <<<NB,       256, 0, stream>>>(p1q, p1scl, zq8, zscl, h_in, rowp, csrs, csrw,
                                          twB, twBlo, tb, out);
}